// Round 13
// baseline (270.467 us; speedup 1.0000x reference)
//
#include <hip/hip_runtime.h>
#include <hip/hip_bf16.h>

// DoubleConv: hypernet 3x3 radius-interp conv x2 + per-item BN+ReLU.
// Round 13: 32x32x16 MFMA (halves LDS bfr reads + MFMA issue + frag loads),
// single-radius in-register lerp (W + precomputed D), full-column blocks,
// wave = 32 o x 256 h.

#define SD 6
#define HD 128
#define HYPER_OUT 294912
#define BN_EPS 1e-5f

typedef unsigned short ushort_t;
typedef __attribute__((ext_vector_type(8)))  short bf16x8;
typedef __attribute__((ext_vector_type(16))) float f32x16;

__device__ inline ushort_t f2bf(float f) {
  union { float f; unsigned u; } v; v.f = f;
  unsigned r = v.u + 0x7fffu + ((v.u >> 16) & 1u);   // RNE
  return (ushort_t)(r >> 16);
}
__device__ inline float bf2f(ushort_t h) {
  union { unsigned u; float f; } v; v.u = ((unsigned)h) << 16; return v.f;
}
__device__ inline unsigned pack2(float a, float b) {
  return (unsigned)f2bf(a) | ((unsigned)f2bf(b) << 16);
}

// r = a + f*d, elementwise on bf16x8, compiler-scheduled cvt_pk
__device__ inline bf16x8 lerp8d(bf16x8 a, bf16x8 d, float f) {
  union U { bf16x8 v; unsigned u[4]; };
  U A, D, R;
  A.v = a; D.v = d;
  #pragma unroll
  for (int i = 0; i < 4; ++i) {
    float alo = __uint_as_float(A.u[i] << 16);
    float ahi = __uint_as_float(A.u[i] & 0xffff0000u);
    float dlo = __uint_as_float(D.u[i] << 16);
    float dhi = __uint_as_float(D.u[i] & 0xffff0000u);
    float rlo = fmaf(f, dlo, alo);
    float rhi = fmaf(f, dhi, ahi);
    __hip_bfloat162 h2 = __float22bfloat162_rn(float2{rlo, rhi});
    R.u[i] = *reinterpret_cast<unsigned*>(&h2);
  }
  return R.v;
}

// As element offset with XOR swizzle (16B-unit low-3 bits ^= row&7)
__device__ inline int as_off(int row, int cu) {    // As[258 rows][16 units of 8]
  return row*128 + ((cu ^ (row & 7)) << 3);
}

// ---------------- e-MLPs: e_all[16][128], row = item*8 + conv*4 + n ----------------
__global__ __launch_bounds__(128) void k_mlp(
    const float* __restrict__ seidel,
    const float* __restrict__ m1_w1, const float* __restrict__ m1_b1,
    const float* __restrict__ m1_w2, const float* __restrict__ m1_b2,
    const float* __restrict__ m2_w1, const float* __restrict__ m2_b1,
    const float* __restrict__ m2_w2, const float* __restrict__ m2_b2,
    float* __restrict__ e_all)
{
  int b = blockIdx.x;                 // 16 blocks
  int item = b >> 3, conv = (b >> 2) & 1, n = b & 3;
  const float* w1 = conv ? m2_w1 : m1_w1;
  const float* b1 = conv ? m2_b1 : m1_b1;
  const float* w2 = conv ? m2_w2 : m1_w2;
  const float* b2 = conv ? m2_b2 : m1_b2;
  int t = threadIdx.x;                // 128
  __shared__ float e1[HD];
  float s = b1[n*HD + t];
  #pragma unroll
  for (int i = 0; i < SD; ++i) s = fmaf(seidel[item*SD + i], w1[(n*SD + i)*HD + t], s);
  e1[t] = fmaxf(s, 0.f);
  __syncthreads();
  float s2 = b2[n*HD + t];
  for (int i = 0; i < HD; ++i) s2 = fmaf(e1[i], w2[(n*HD + i)*HD + t], s2);
  e_all[b*HD + t] = fmaxf(s2, 0.f);
}

// ---------------- hyper GEMM -> wb_lin[j][16] bf16 (coalesced writes) --------------
__global__ __launch_bounds__(256) void k_hyper(
    const float* __restrict__ e_all, const float* __restrict__ hyper_w,
    const float* __restrict__ hyper_b, ushort_t* __restrict__ wb_lin)
{
  __shared__ float es[16*HD];
  int t = threadIdx.x;
  for (int f = t; f < 16*HD; f += 256) es[f] = e_all[f];
  __syncthreads();
  int j = blockIdx.x*256 + t;         // 1152 * 256 = 294912
  float val[16];
  #pragma unroll
  for (int r = 0; r < 16; ++r) val[r] = 0.f;
  for (int i = 0; i < HD; ++i) {
    float hw = hyper_w[(size_t)i*HYPER_OUT + j];
    #pragma unroll
    for (int r = 0; r < 16; ++r) val[r] = fmaf(es[r*HD + i], hw, val[r]);
  }
  float bias = hyper_b[j];
  uint4 u0, u1;
  u0.x = pack2(val[0]+bias,  val[1]+bias);
  u0.y = pack2(val[2]+bias,  val[3]+bias);
  u0.z = pack2(val[4]+bias,  val[5]+bias);
  u0.w = pack2(val[6]+bias,  val[7]+bias);
  u1.x = pack2(val[8]+bias,  val[9]+bias);
  u1.y = pack2(val[10]+bias, val[11]+bias);
  u1.z = pack2(val[12]+bias, val[13]+bias);
  u1.w = pack2(val[14]+bias, val[15]+bias);
  *reinterpret_cast<uint4*>(wb_lin + (size_t)j*16)     = u0;
  *reinterpret_cast<uint4*>(wb_lin + (size_t)j*16 + 8) = u1;
}

// ---------------- fused prep: transpose x (blocks 0..4095) + repack (4096..5247) ----
// transpose: [item][c][h][w] f32 -> [item][w][h][c] bf16
// repack -> 32x32x16 A-frag-linear W and D = W[nr+1]-W[nr] (D[7]=0):
//   wbW/wbD[(conv*2+item)][nr][kj][slice(24 = ki*8 + c16)][oblk(4)][lane(64)][8]
//   lane = (o&31) | ((c>>3)&1)<<5 ; elems j = c&7 ; k-within-slice = (lane>>5)*8+j
__global__ __launch_bounds__(256) void k_prep(
    const float* __restrict__ x, ushort_t* __restrict__ xt,
    const ushort_t* __restrict__ wb_lin,
    ushort_t* __restrict__ wbW, ushort_t* __restrict__ wbD)
{
  __shared__ __align__(16) float tileF[64][65];     // transpose tile
  __shared__ ushort_t ldsN[16][256];                // repack: next-radius values
  int b = blockIdx.x;
  int t = threadIdx.x;
  if (b < 4096) {
    int wt = b & 3, ct = (b >> 2) & 1, z = b >> 3;
    int h = z & 255, item = z >> 8;
    {
      int cl = t >> 2, wk = (t & 3) << 4;
      const float* sp = x + (((size_t)item*128 + ct*64 + cl)*256 + h)*256 + wt*64 + wk;
      #pragma unroll
      for (int k = 0; k < 16; k += 4) {
        float4 v = *reinterpret_cast<const float4*>(sp + k);
        tileF[cl][wk+k] = v.x; tileF[cl][wk+k+1] = v.y;
        tileF[cl][wk+k+2] = v.z; tileF[cl][wk+k+3] = v.w;
      }
    }
    __syncthreads();
    {
      int wl = t >> 2, ck = (t & 3) << 4;
      ushort_t* dp = xt + (((size_t)item*256 + wt*64 + wl)*256 + h)*128 + ct*64 + ck;
      uint4 u0, u1;
      u0.x = pack2(tileF[ck+0][wl],  tileF[ck+1][wl]);
      u0.y = pack2(tileF[ck+2][wl],  tileF[ck+3][wl]);
      u0.z = pack2(tileF[ck+4][wl],  tileF[ck+5][wl]);
      u0.w = pack2(tileF[ck+6][wl],  tileF[ck+7][wl]);
      u1.x = pack2(tileF[ck+8][wl],  tileF[ck+9][wl]);
      u1.y = pack2(tileF[ck+10][wl], tileF[ck+11][wl]);
      u1.z = pack2(tileF[ck+12][wl], tileF[ck+13][wl]);
      u1.w = pack2(tileF[ck+14][wl], tileF[ck+15][wl]);
      *reinterpret_cast<uint4*>(dp)     = u0;
      *reinterpret_cast<uint4*>(dp + 8) = u1;
    }
  } else {
    int i = b - 4096;
    int chunk = i & 15;               // 0..15 (u-groups of 4)
    int tap   = i >> 4;               // 0..71
    int nr = tap / 9, kk = tap % 9;
    int ki = kk / 3, kj = kk % 3;
    int nrn = (nr < 7) ? nr + 1 : 7;
    ushort_t (*lds)[256] = reinterpret_cast<ushort_t(*)[256]>(tileF);
    int uv = chunk*256 + t;           // u = uv>>6, v = uv&63
    size_t j  = (size_t)uv*72 + nr*9 + kk;
    size_t j2 = (size_t)uv*72 + nrn*9 + kk;
    uint4 q0 = *reinterpret_cast<const uint4*>(wb_lin + j*16);
    uint4 q1 = *reinterpret_cast<const uint4*>(wb_lin + j*16 + 8);
    uint4 n0 = *reinterpret_cast<const uint4*>(wb_lin + j2*16);
    uint4 n1 = *reinterpret_cast<const uint4*>(wb_lin + j2*16 + 8);
    const ushort_t* pr0 = reinterpret_cast<const ushort_t*>(&q0);
    const ushort_t* pr1 = reinterpret_cast<const ushort_t*>(&q1);
    const ushort_t* pn0 = reinterpret_cast<const ushort_t*>(&n0);
    const ushort_t* pn1 = reinterpret_cast<const ushort_t*>(&n1);
    #pragma unroll
    for (int r = 0; r < 8; ++r) { lds[r][t]  = pr0[r]; ldsN[r][t]  = pn0[r]; }
    #pragma unroll
    for (int r = 0; r < 8; ++r) { lds[r+8][t] = pr1[r]; ldsN[r+8][t] = pn1[r]; }
    __syncthreads();
    #pragma unroll
    for (int it = 0; it < 2; ++it) {
      int idx = it*256 + t;           // 512 row-segments (8 consecutive c at fixed o)
      int row = idx >> 3, seg = idx & 7;
      int p = row >> 2, ul = row & 3;
      int item = p >> 3, conv = (p >> 2) & 1, n = p & 3;
      int o  = (n >> 1)*64 + chunk*4 + ul;
      int c8 = (n & 1)*8 + seg;        // c/8 in 0..15
      int slice = ki*8 + (c8 >> 1);    // ki*8 + c16
      int lane  = (o & 31) + (c8 & 1)*32;
      int oblk  = o >> 5;
      uint4 v = *reinterpret_cast<const uint4*>(&lds[p][ul*64 + seg*8]);
      uint4 d4;
      {
        const ushort_t* pw = reinterpret_cast<const ushort_t*>(&v);
        const ushort_t* pnx = &ldsN[p][ul*64 + seg*8];
        ushort_t* pd = reinterpret_cast<ushort_t*>(&d4);
        #pragma unroll
        for (int e = 0; e < 8; ++e) pd[e] = f2bf(bf2f(pnx[e]) - bf2f(pw[e]));
      }
      size_t off = (size_t)(conv*2 + item)*1179648
                 + ((((size_t)nr*3 + kj)*24 + slice)*4 + oblk)*512 + lane*8;
      *reinterpret_cast<uint4*>(wbW + off) = v;
      *reinterpret_cast<uint4*>(wbD + off) = d4;
    }
  }
}

// ---------------- MFMA conv: 32x32x16, full-column block, 4 o-block waves ----------
// src [item][w][h][c] bf16 ; wbW/wbD 32x32-frag-linear
// dst [item][w][h][o] bf16 pre-BN ; ps/p2 partials [512][128]
// grid 512 (XCD-swizzled), 256 threads = 4 waves, each 32 o x 256 h.
template<bool BN_IN>
__global__ __launch_bounds__(256, 2) void k_conv(
    const ushort_t* __restrict__ src,
    const ushort_t* __restrict__ wbW, const ushort_t* __restrict__ wbD,
    const float* __restrict__ bn_a, const float* __restrict__ bn_c,
    ushort_t* __restrict__ dst, float* __restrict__ ps, float* __restrict__ p2)
{
  __shared__ __align__(16) ushort_t As[258*128];    // 66,048 B (swizzled)
  __shared__ float sbn[256];
  int bid = blockIdx.x;
  int wgid = ((bid & 7) << 6) | (bid >> 3);          // XCD-contiguous, 512 blocks
  int item = wgid >> 8;
  int w    = wgid & 255;
  int t = threadIdx.x;
  int lane = t & 63, wid = t >> 6;
  int l31 = lane & 31, kh = lane >> 5;

  float pos = fminf(fmaxf((w + 0.5f)*0.03125f - 0.5f, 0.f), 7.f);
  int i0 = (int)pos; float fr = pos - (float)i0;

  if constexpr (BN_IN) {
    sbn[t] = (t < 128) ? bn_a[item*128 + t] : bn_c[item*128 + (t - 128)];
    __syncthreads();                                 // sbn visible before stage_as
  }

  // per-lane weight fragment base (wave owns oblk = wid)
  const ushort_t* wpW = wbW + (size_t)item*1179648 + (size_t)i0*147456
                      + wid*512 + lane*8;
  const ushort_t* wpD = wbD + (size_t)item*1179648 + (size_t)i0*147456
                      + wid*512 + lane*8;

  f32x16 acc[8];
  #pragma unroll
  for (int a = 0; a < 8; ++a)
    #pragma unroll
    for (int b = 0; b < 16; ++b)
      acc[a][b] = 0.f;

  // stage As (258 halo rows, full column) for a given kj
  auto stage_as = [&](int kj) {
    int wc = w + kj - 1;
    bool valid = (wc >= 0) && (wc < 256);
    const ushort_t* sb = src + ((size_t)item*256 + (valid ? wc : 0))*32768;
    for (int f = t; f < 258*16; f += 256) {
      int row = f >> 4, cu = f & 15;
      uint4 v = make_uint4(0u, 0u, 0u, 0u);
      if (valid) {
        int hg = (row + 255) & 255;                  // circular pad in H
        v = *reinterpret_cast<const uint4*>(sb + ((size_t)hg << 7) + (cu << 3));
        if constexpr (BN_IN) {
          ushort_t* pv = reinterpret_cast<ushort_t*>(&v);
          int c0 = cu << 3;
          #pragma unroll
          for (int jj = 0; jj < 8; ++jj) {
            float xv = bf2f(pv[jj]);
            xv = fmaxf(fmaf(sbn[c0 + jj], xv, sbn[128 + c0 + jj]), 0.f);
            pv[jj] = f2bf(xv);
          }
        }
      }
      *reinterpret_cast<uint4*>(&As[as_off(row, cu)]) = v;
    }
  };

  bf16x8 rwA, rdA, rwB, rdB, lw;
  rwA = *reinterpret_cast<const bf16x8*>(wpW);       // prologue (s = 0)
  rdA = *reinterpret_cast<const bf16x8*>(wpD);

  for (int kj = 0; kj < 3; ++kj) {
    __syncthreads();                                 // prev kj's readers done
    stage_as(kj);
    __syncthreads();                                 // As visible
    #pragma unroll
    for (int sl = 0; sl < 24; ++sl) {                // slice = ki*8 + c16
      int ki = sl >> 3, c16 = sl & 7;
      int s = kj*24 + sl;
      size_t nxt = (size_t)((s + 1 < 72) ? s + 1 : 71)*2048;
      if ((sl & 1) == 0) {
        rwB = *reinterpret_cast<const bf16x8*>(wpW + nxt);
        rdB = *reinterpret_cast<const bf16x8*>(wpD + nxt);
        lw = lerp8d(rwA, rdA, fr);
      } else {
        rwA = *reinterpret_cast<const bf16x8*>(wpW + nxt);
        rdA = *reinterpret_cast<const bf16x8*>(wpD + nxt);
        lw = lerp8d(rwB, rdB, fr);
      }
      bf16x8 bfr[8];
      #pragma unroll
      for (int nt = 0; nt < 8; ++nt)
        bfr[nt] = *reinterpret_cast<const bf16x8*>(
            &As[as_off(nt*32 + l31 + ki, c16*2 + kh)]);
      #pragma unroll
      for (int nt = 0; nt < 8; ++nt)
        acc[nt] = __builtin_amdgcn_mfma_f32_32x32x16_bf16(
            lw, bfr[nt], acc[nt], 0, 0, 0);
    }
  }

  // epilogue: store bf16 [h][o], BN partials
  // C/D layout (m74/m101): col(n=h) = lane&31, row(m=o) = (reg&3)+8*(reg>>2)+4*(lane>>5)
  ushort_t* yb = dst + ((size_t)item*256 + w)*32768;
  float ssum[4][4], s2sum[4][4];
  #pragma unroll
  for (int a = 0; a < 4; ++a)
    #pragma unroll
    for (int b = 0; b < 4; ++b) { ssum[a][b] = 0.f; s2sum[a][b] = 0.f; }
  #pragma unroll
  for (int nt = 0; nt < 8; ++nt) {
    int h = nt*32 + l31;
    #pragma unroll
    for (int rq = 0; rq < 4; ++rq) {
      float v[4];
      #pragma unroll
      for (int r4 = 0; r4 < 4; ++r4) {
        v[r4] = acc[nt][rq*4 + r4];
        ssum[rq][r4] += v[r4];
        s2sum[rq][r4] = fmaf(v[r4], v[r4], s2sum[rq][r4]);
      }
      int o0 = wid*32 + rq*8 + kh*4;
      uint2 u; u.x = pack2(v[0], v[1]); u.y = pack2(v[2], v[3]);
      *reinterpret_cast<uint2*>(yb + (size_t)h*128 + o0) = u;
    }
  }
  #pragma unroll
  for (int rq = 0; rq < 4; ++rq)
    #pragma unroll
    for (int r4 = 0; r4 < 4; ++r4)
      #pragma unroll
      for (int m = 1; m < 32; m <<= 1) {             // reduce over h (lane&31)
        ssum[rq][r4]  += __shfl_xor(ssum[rq][r4], m);
        s2sum[rq][r4] += __shfl_xor(s2sum[rq][r4], m);
      }
  __syncthreads();                                   // reuse As as scratch
  float* redS  = reinterpret_cast<float*>(As);       // [128] o-linear
  float* redS2 = redS + 128;
  if (l31 == 0) {
    #pragma unroll
    for (int rq = 0; rq < 4; ++rq)
      #pragma unroll
      for (int r4 = 0; r4 < 4; ++r4) {
        int o = wid*32 + rq*8 + kh*4 + r4;           // each o owned by ONE lane
        redS [o] = ssum[rq][r4];
        redS2[o] = s2sum[rq][r4];
      }
  }
  __syncthreads();
  if (t < 128) {
    size_t bi = (size_t)item*256 + w;
    ps[bi*128 + t] = redS[t];
    p2[bi*128 + t] = redS2[t];
  }
}

// ---------------- reduce partials -> BN affine: 256 blocks (item x channel) --------
__global__ __launch_bounds__(256) void k_bnapply(
    const float* __restrict__ ps, const float* __restrict__ p2,
    const float* __restrict__ gamma, const float* __restrict__ beta,
    float* __restrict__ bn_a, float* __restrict__ bn_c)
{
  int item = blockIdx.x >> 7, o = blockIdx.x & 127;
  int t = threadIdx.x;
  size_t bi = (size_t)(item*256 + t)*128 + o;
  float s  = ps[bi];
  float s2 = p2[bi];
  #pragma unroll
  for (int m = 1; m < 64; m <<= 1) { s += __shfl_xor(s, m); s2 += __shfl_xor(s2, m); }
  __shared__ float rs[4], rs2[4];
  if ((t & 63) == 0) { rs[t >> 6] = s; rs2[t >> 6] = s2; }
  __syncthreads();
  if (t == 0) {
    s  = rs[0] + rs[1] + rs[2] + rs[3];
    s2 = rs2[0] + rs2[1] + rs2[2] + rs2[3];
    float mu  = s  * (1.f/65536.f);
    float var = s2 * (1.f/65536.f) - mu*mu;
    float a = gamma[o] * rsqrtf(var + BN_EPS);
    bn_a[item*128 + o] = a;
    bn_c[item*128 + o] = beta[o] - a*mu;
  }
}

// ---------------- final: BN2+ReLU + transpose [item][w][h][o] bf16 -> NCHW f32 ------
__global__ __launch_bounds__(256) void k_final(
    const ushort_t* __restrict__ y, const float* __restrict__ bn_a,
    const float* __restrict__ bn_c, float* __restrict__ out)
{
  __shared__ float tile[64][65];      // [w][o]
  int wt = blockIdx.x, ot = blockIdx.y;
  int h = blockIdx.z & 255, item = blockIdx.z >> 8;
  int t = threadIdx.x;
  {
    int wl = t >> 2, ck = (t & 3) << 4;
    const ushort_t* sp = y + (((size_t)item*256 + wt*64 + wl)*256 + h)*128 + ot*64 + ck;
    uint4 a = *reinterpret_cast<const uint4*>(sp);
    uint4 b = *reinterpret_cast<const uint4*>(sp + 8);
    const ushort_t* pa = reinterpret_cast<const ushort_t*>(&a);
    const ushort_t* pb = reinterpret_cast<const ushort_t*>(&b);
    #pragma unroll
    for (int k = 0; k < 8; ++k) {
      int o = ot*64 + ck + k;
      tile[wl][ck + k] = fmaxf(fmaf(bn_a[item*128 + o], bf2f(pa[k]), bn_c[item*128 + o]), 0.f);
    }
    #pragma unroll
    for (int k = 0; k < 8; ++k) {
      int o = ot*64 + ck + 8 + k;
      tile[wl][ck + 8 + k] = fmaxf(fmaf(bn_a[item*128 + o], bf2f(pb[k]), bn_c[item*128 + o]), 0.f);
    }
  }
  __syncthreads();
  {
    int ol = t >> 2, wk = (t & 3) << 4;
    float* dp = out + (((size_t)item*128 + ot*64 + ol)*256 + h)*256 + wt*64 + wk;
    #pragma unroll
    for (int k = 0; k < 16; k += 4) {
      float4 v;
      v.x = tile[wk+k][ol];   v.y = tile[wk+k+1][ol];
      v.z = tile[wk+k+2][ol]; v.w = tile[wk+k+3][ol];
      *reinterpret_cast<float4*>(dp + k) = v;
    }
  }
}

extern "C" void kernel_launch(void* const* d_in, const int* in_sizes, int n_in,
                              void* d_out, int out_size, void* d_ws, size_t ws_size,
                              hipStream_t stream) {
  const float* x       = (const float*)d_in[0];
  const float* seidel  = (const float*)d_in[1];
  const float* m1_w1   = (const float*)d_in[2];
  const float* m1_b1   = (const float*)d_in[3];
  const float* m1_w2   = (const float*)d_in[4];
  const float* m1_b2   = (const float*)d_in[5];
  const float* m2_w1   = (const float*)d_in[6];
  const float* m2_b1   = (const float*)d_in[7];
  const float* m2_w2   = (const float*)d_in[8];
  const float* m2_b2   = (const float*)d_in[9];
  const float* hyper_w = (const float*)d_in[10];
  const float* hyper_b = (const float*)d_in[11];
  const float* bn1_g   = (const float*)d_in[12];
  const float* bn1_b   = (const float*)d_in[13];
  const float* bn2_g   = (const float*)d_in[14];
  const float* bn2_b   = (const float*)d_in[15];

  char* ws = (char*)d_ws;
  float*    e_all  = (float*)ws;                                    // 8,192
  ushort_t* wb_lin = (ushort_t*)(ws + 8192);                        // 9,437,184
  ushort_t* wbW    = (ushort_t*)(ws + 9445376);                     // 9,437,184
  ushort_t* wbD    = (ushort_t*)(ws + 18882560);                    // 9,437,184
  ushort_t* xt     = (ushort_t*)(ws + 28319744);                    // 33,554,432
  ushort_t* y1     = (ushort_t*)(ws + 61874176);                    // 33,554,432
  ushort_t* y2     = (ushort_t*)(ws + 95428608);                    // 33,554,432
  float*    ps     = (float*)(ws + 128983040);                      // 262,144
  float*    p2     = (float*)(ws + 129245184);                      // 262,144
  float*    bnb    = (float*)(ws + 129507328);                      // 4 KB
  float* bn1_a = bnb,        *bn1_c = bnb + 256;
  float* bn2_a = bnb + 512,  *bn2_c = bnb + 768;

  k_mlp<<<16, 128, 0, stream>>>(seidel, m1_w1, m1_b1, m1_w2, m1_b2,
                                m2_w1, m2_b1, m2_w2, m2_b2, e_all);
  k_hyper<<<HYPER_OUT/256, 256, 0, stream>>>(e_all, hyper_w, hyper_b, wb_lin);
  k_prep<<<5248, 256, 0, stream>>>(x, xt, wb_lin, wbW, wbD);

  k_conv<false><<<512, 256, 0, stream>>>(xt, wbW, wbD, nullptr, nullptr, y1, ps, p2);
  k_bnapply<<<256, 256, 0, stream>>>(ps, p2, bn1_g, bn1_b, bn1_a, bn1_c);

  k_conv<true><<<512, 256, 0, stream>>>(y1, wbW + 2359296, wbD + 2359296,
                                        bn1_a, bn1_c, y2, ps, p2);
  k_bnapply<<<256, 256, 0, stream>>>(ps, p2, bn2_g, bn2_b, bn2_a, bn2_c);
  k_final<<<dim3(4, 2, 512), 256, 0, stream>>>(y2, bn2_a, bn2_c, (float*)d_out);
}